// Round 1
// baseline (316.260 us; speedup 1.0000x reference)
//
#include <hip/hip_runtime.h>
#include <cstddef>

#define NOBJ   16
#define FEAT   512
#define VIS    2048
#define NTGT   24
#define MROWS  4096    // 128 * 32 rows into the MLP
#define EROWS  32768   // 128 * 16 * 16 edge rows

// ---------------------------------------------------------------------------
// Generic fp32 GEMM: C[M x N] = opt_relu(A[M x K] @ W[K x N] + bias[N])
// 64x64 block tile, 256 threads, 4x4 microtile, K-step 16, LDS staged.
// ---------------------------------------------------------------------------
__global__ __launch_bounds__(256)
void gemm_tile64(const float* __restrict__ A, const float* __restrict__ W,
                 const float* __restrict__ bias, float* __restrict__ C,
                 int K, int N, int relu)
{
    __shared__ float As[16][68];   // [k][m], padded to 68 (272B rows, 16B aligned)
    __shared__ float Bs[16][68];   // [k][n]
    const int t  = threadIdx.x;
    const int m0 = blockIdx.y * 64;
    const int n0 = blockIdx.x * 64;
    const int tx = t & 15, ty = t >> 4;
    const int arow = t >> 2;          // 0..63
    const int akq  = (t & 3) << 2;    // 0,4,8,12
    const int bkr  = t >> 4;          // 0..15
    const int bnq  = (t & 15) << 2;   // 0..60

    float acc[4][4] = {{0.f, 0.f, 0.f, 0.f}};

    for (int k0 = 0; k0 < K; k0 += 16) {
        float4 a = *reinterpret_cast<const float4*>(
            &A[(size_t)(m0 + arow) * K + k0 + akq]);
        As[akq + 0][arow] = a.x;
        As[akq + 1][arow] = a.y;
        As[akq + 2][arow] = a.z;
        As[akq + 3][arow] = a.w;
        float4 b = *reinterpret_cast<const float4*>(
            &W[(size_t)(k0 + bkr) * N + n0 + bnq]);
        *reinterpret_cast<float4*>(&Bs[bkr][bnq]) = b;
        __syncthreads();
        #pragma unroll
        for (int k = 0; k < 16; ++k) {
            float4 av = *reinterpret_cast<const float4*>(&As[k][ty << 2]);
            float4 bv = *reinterpret_cast<const float4*>(&Bs[k][tx << 2]);
            const float am[4] = {av.x, av.y, av.z, av.w};
            const float bm[4] = {bv.x, bv.y, bv.z, bv.w};
            #pragma unroll
            for (int i = 0; i < 4; ++i)
                #pragma unroll
                for (int j = 0; j < 4; ++j)
                    acc[i][j] = fmaf(am[i], bm[j], acc[i][j]);
        }
        __syncthreads();
    }

    #pragma unroll
    for (int i = 0; i < 4; ++i) {
        const int m = m0 + (ty << 2) + i;
        #pragma unroll
        for (int j = 0; j < 4; ++j) {
            const int n = n0 + (tx << 2) + j;
            float v = acc[i][j] + bias[n];
            if (relu) v = fmaxf(v, 0.f);
            C[(size_t)m * N + n] = v;
        }
    }
}

// ---------------------------------------------------------------------------
// Edge projection factorization:
//   Ap[bt,i,:] = node[bt, i,      :] @ wr[0:512, :]      (subject half)
//   Bp[bt,j,:] = node[bt, 16 + j, :] @ wr[512:1024, :]   (object half)
// node is (128, 32, 512) flat = (4096, 512). Ap/Bp are (2048, 24).
// blockIdx.y = half (0 subj / 1 obj); each block does 8 rows x 24 cols.
// ---------------------------------------------------------------------------
__global__ __launch_bounds__(192)
void relproj(const float* __restrict__ node, const float* __restrict__ wr,
             float* __restrict__ Ap, float* __restrict__ Bp)
{
    __shared__ float rows[8][FEAT];
    const int half = blockIdx.y;
    const int r0   = blockIdx.x * 8;   // 0..2040
    const int t    = threadIdx.x;
    for (int idx = t; idx < 8 * FEAT; idx += 192) {
        const int rr = idx >> 9;
        const int k  = idx & 511;
        const int g  = r0 + rr;            // 0..2047
        const int bt = g >> 4;
        const int i  = g & 15;
        rows[rr][k] = node[((size_t)bt * 32 + half * NOBJ + i) * FEAT + k];
    }
    __syncthreads();
    const int c  = t % NTGT;   // 0..23
    const int rr = t / NTGT;   // 0..7
    const float* w = wr + (size_t)half * FEAT * NTGT;
    float s = 0.f;
    for (int k = 0; k < FEAT; ++k)
        s = fmaf(rows[rr][k], w[(size_t)k * NTGT + c], s);
    float* dst = half ? Bp : Ap;
    dst[(size_t)(r0 + rr) * NTGT + c] = s;
}

// ---------------------------------------------------------------------------
// Fused: logits assembly + write, tgt copy, weighted-CE partial reduction.
// One thread per edge row (32768 rows, 24 classes).
// ---------------------------------------------------------------------------
__global__ __launch_bounds__(256)
void out_loss_kernel(const float* __restrict__ Ap, const float* __restrict__ Bp,
                     const float* __restrict__ br, const int* __restrict__ tgt,
                     float* __restrict__ out, float* __restrict__ out_tgt,
                     float* __restrict__ acc)
{
    const int r   = blockIdx.x * 256 + threadIdx.x;   // 0..32767
    const int bt  = r >> 8;
    const int rem = r & 255;
    const int i   = rem >> 4;
    const int j   = rem & 15;
    const float* ap = Ap + ((size_t)bt * NOBJ + i) * NTGT;
    const float* bp = Bp + ((size_t)bt * NOBJ + j) * NTGT;
    const int tg = tgt[r];

    float vals[NTGT];
    float mx = -1e30f, vtg = 0.f;
    #pragma unroll
    for (int t = 0; t < NTGT; ++t) {
        const float v = ap[t] + bp[t] + br[t];
        vals[t] = v;
        mx = fmaxf(mx, v);
        if (t == tg) vtg = v;   // static t, runtime tg -> cndmask, no scratch
    }
    float se = 0.f;
    #pragma unroll
    for (int t = 0; t < NTGT; ++t) se += expf(vals[t] - mx);
    const float lse = mx + logf(se);

    #pragma unroll
    for (int t = 0; t < NTGT; ++t) out[(size_t)r * NTGT + t] = vals[t];
    out_tgt[r] = (float)tg;

    const float wcl = (tg == 0) ? 1.f : 100.f;
    float p1 = wcl * (lse - vtg);
    float p2 = wcl;
    #pragma unroll
    for (int off = 32; off > 0; off >>= 1) {
        p1 += __shfl_down(p1, off);
        p2 += __shfl_down(p2, off);
    }
    __shared__ float s1[4], s2[4];
    const int lane = threadIdx.x & 63;
    const int wid  = threadIdx.x >> 6;
    if (lane == 0) { s1[wid] = p1; s2[wid] = p2; }
    __syncthreads();
    if (threadIdx.x == 0) {
        atomicAdd(&acc[0], s1[0] + s1[1] + s1[2] + s1[3]);
        atomicAdd(&acc[1], s2[0] + s2[1] + s2[2] + s2[3]);
    }
}

__global__ void zero_acc(float* acc) { acc[0] = 0.f; acc[1] = 0.f; }

__global__ void final_loss(const float* __restrict__ acc, float* __restrict__ loss)
{
    loss[0] = acc[0] / acc[1];
}

// ---------------------------------------------------------------------------
extern "C" void kernel_launch(void* const* d_in, const int* in_sizes, int n_in,
                              void* d_out, int out_size, void* d_ws, size_t ws_size,
                              hipStream_t stream)
{
    const float* src = (const float*)d_in[0];   // (4096, 2048) after identity reshape
    const int*   tgt = (const int*)d_in[1];     // 32768
    const float* w1  = (const float*)d_in[2];   // (2048, 512)
    const float* b1  = (const float*)d_in[3];
    const float* w2  = (const float*)d_in[4];   // (512, 512)
    const float* b2  = (const float*)d_in[5];
    const float* wf  = (const float*)d_in[6];   // (512, 512)
    const float* bf  = (const float*)d_in[7];
    const float* wr  = (const float*)d_in[8];   // (1024, 24)
    const float* br  = (const float*)d_in[9];   // (24)

    float* ws  = (float*)d_ws;
    float* h1  = ws;                   // 4096*512 (reused for node_feats)
    float* h2  = ws + 2097152;         // 4096*512
    float* Ap  = ws + 4194304;         // 2048*24
    float* Bp  = ws + 4243456;         // 2048*24
    float* acc = ws + 4292608;         // 2 floats

    float* out_logits = (float*)d_out;                       // 786432
    float* out_tgt    = out_logits + (size_t)EROWS * NTGT;   // 32768
    float* out_lossp  = out_tgt + EROWS;                     // 1

    zero_acc<<<1, 1, 0, stream>>>(acc);
    // fc_vis layer 1 (ReLU): (4096x2048)@(2048x512)
    gemm_tile64<<<dim3(FEAT / 64, MROWS / 64), 256, 0, stream>>>(
        src, w1, b1, h1, VIS, FEAT, 1);
    // fc_vis layer 2: (4096x512)@(512x512)
    gemm_tile64<<<dim3(FEAT / 64, MROWS / 64), 256, 0, stream>>>(
        h1, w2, b2, h2, FEAT, FEAT, 0);
    // fc_fusion: (4096x512)@(512x512) -> node_feats (into h1)
    gemm_tile64<<<dim3(FEAT / 64, MROWS / 64), 256, 0, stream>>>(
        h2, wf, bf, h1, FEAT, FEAT, 0);
    // factored fc_rel halves
    relproj<<<dim3(256, 2), 192, 0, stream>>>(h1, wr, Ap, Bp);
    // logits + tgt + weighted CE partials
    out_loss_kernel<<<EROWS / 256, 256, 0, stream>>>(
        Ap, Bp, br, tgt, out_logits, out_tgt, acc);
    final_loss<<<1, 1, 0, stream>>>(acc, out_lossp);
}

// Round 2
// 172.266 us; speedup vs baseline: 1.8359x; 1.8359x over previous
//
#include <hip/hip_runtime.h>
#include <cstddef>
#include <cstdint>

#define NOBJ   16
#define FEAT   512
#define VIS    2048
#define NTGT   24
#define MROWS  4096
#define EROWS  32768

typedef __attribute__((ext_vector_type(8))) short short8;
typedef __attribute__((ext_vector_type(4))) float f32x4;

__device__ __forceinline__ float bf2f(unsigned short u) {
    union { unsigned int i; float f; } v; v.i = ((unsigned int)u) << 16; return v.f;
}
__device__ __forceinline__ unsigned short f2bf(float f) {
    union { float f; unsigned int i; } v; v.f = f;
    const unsigned int x = v.i;
    return (unsigned short)((x + 0x7fffu + ((x >> 16) & 1u)) >> 16);  // RTNE
}
__device__ __forceinline__ short8 pack8(const float4 a, const float4 b) {
    short8 r;
    r[0] = (short)f2bf(a.x); r[1] = (short)f2bf(a.y);
    r[2] = (short)f2bf(a.z); r[3] = (short)f2bf(a.w);
    r[4] = (short)f2bf(b.x); r[5] = (short)f2bf(b.y);
    r[6] = (short)f2bf(b.z); r[7] = (short)f2bf(b.w);
    return r;
}

// ---------------------------------------------------------------------------
__global__ void zero_kernel(float* __restrict__ p, int n) {
    const int i = blockIdx.x * 256 + threadIdx.x;
    if (i < n) p[i] = 0.f;
}

// w1 (2048x512 f32) -> w1t (512x2048 bf16), transposed
__global__ __launch_bounds__(256)
void wtrans(const float* __restrict__ w1, unsigned short* __restrict__ w1t) {
    __shared__ float tile[32][33];
    const int k0 = blockIdx.x * 32;           // K dim (2048)
    const int n0 = blockIdx.y * 32;           // N dim (512)
    const int tx = threadIdx.x & 31, ty = threadIdx.x >> 5;   // ty 0..7
    #pragma unroll
    for (int r = 0; r < 32; r += 8)
        tile[ty + r][tx] = w1[(size_t)(k0 + ty + r) * FEAT + n0 + tx];
    __syncthreads();
    #pragma unroll
    for (int r = 0; r < 32; r += 8)
        w1t[(size_t)(n0 + ty + r) * VIS + k0 + tx] = f2bf(tile[tx][ty + r]);
}

// ---------------------------------------------------------------------------
// Weight chain stage 1: t1[h][k][c] = sum_j rowk[j] * wr[(h*512+j)*24+c]
// rowk = wf[k][:] for k<512, = bf[:] for k==512.  t1 stride 32 cols.
__global__ __launch_bounds__(256)
void wchain1(const float* __restrict__ wf, const float* __restrict__ bfv,
             const float* __restrict__ wr, float* __restrict__ t1) {
    const int c    = threadIdx.x;                       // 0..31
    const int krow = blockIdx.x * 8 + threadIdx.y;      // 0..519
    const int h    = blockIdx.z;
    const int j0   = blockIdx.y * 128;
    if (krow > 512) return;
    const float* rowp = (krow < 512) ? (wf + (size_t)krow * FEAT) : bfv;
    const int ce = (c < NTGT) ? c : NTGT - 1;
    const float* wrp = wr + ((size_t)h * FEAT + j0) * NTGT + ce;
    float s = 0.f;
    #pragma unroll 8
    for (int j = 0; j < 128; ++j)
        s = fmaf(rowp[j0 + j], wrp[(size_t)j * NTGT], s);
    if (c < NTGT) atomicAdd(&t1[((size_t)h * 513 + krow) * 32 + c], s);
}

// Stage 2: wAB[h][r][c] = sum_k rowr[k] * t1[h][k][c]  (+ t1[h][512][c] at r==512)
// rowr = w2[r][:] for r<512, = b2[:] for r==512.  Row 512 of wAB = bias cA/cB.
__global__ __launch_bounds__(256)
void wchain2(const float* __restrict__ w2, const float* __restrict__ b2,
             const float* __restrict__ t1, float* __restrict__ wAB) {
    const int c  = threadIdx.x;
    const int r  = blockIdx.x * 8 + threadIdx.y;
    const int h  = blockIdx.z;
    const int k0 = blockIdx.y * 128;
    if (r > 512) return;
    const float* rowp = (r < 512) ? (w2 + (size_t)r * FEAT) : b2;
    const int ce = (c < NTGT) ? c : NTGT - 1;
    const float* tp = t1 + ((size_t)h * 513 + k0) * 32 + ce;
    float s = 0.f;
    #pragma unroll 8
    for (int k = 0; k < 128; ++k)
        s = fmaf(rowp[k0 + k], tp[(size_t)k * 32], s);
    if (r == 512 && blockIdx.y == 0)
        s += t1[((size_t)h * 513 + 512) * 32 + ce];
    if (c < NTGT) atomicAdd(&wAB[((size_t)h * 513 + r) * 32 + c], s);
}

// ---------------------------------------------------------------------------
// GEMM1: h = relu(src(4096x2048 f32->bf16) @ w1 + b1), B from w1t (512x2048 bf16).
// BM=128 BN=64 BK=64, 4 waves (2x2), 16x16x32 bf16 MFMA, double-buffered LDS,
// XOR-swizzled rows (chunk ^= row&7) on both write and read sides.
__global__ __launch_bounds__(256)
void gemm1(const float* __restrict__ src, const unsigned short* __restrict__ w1t,
           const float* __restrict__ b1, unsigned short* __restrict__ h) {
    __shared__ __align__(16) unsigned short As[2][128 * 64];
    __shared__ __align__(16) unsigned short Bs[2][64 * 64];

    // XCD-aware remap: 8 column-blocks of one row-panel -> same XCD.
    const int bid = blockIdx.x;
    const int xcd = bid & 7;
    const int k8  = bid >> 3;              // 0..31
    const int xb  = k8 & 7;                // col block 0..7
    const int yb  = (xcd << 2) | (k8 >> 3);// row block 0..31
    const int m0 = yb * 128;
    const int n0 = xb * 64;

    const int tid  = threadIdx.x;
    const int lane = tid & 63;
    const int wid  = tid >> 6;
    const int wr = wid >> 1, wc = wid & 1;

    f32x4  acc[4][2] = {};
    float4 areg[4][2];
    short8 breg[2];

    // prologue: load tile 0 -> regs -> LDS buf 0
    #pragma unroll
    for (int q = 0; q < 4; ++q) {
        const int s = q * 256 + tid, row = s >> 3, c = s & 7, cd = c ^ (row & 7);
        const float* gp = src + (size_t)(m0 + row) * VIS + (cd << 3);
        areg[q][0] = *reinterpret_cast<const float4*>(gp);
        areg[q][1] = *reinterpret_cast<const float4*>(gp + 4);
    }
    #pragma unroll
    for (int q = 0; q < 2; ++q) {
        const int s = q * 256 + tid, n = s >> 3, c = s & 7, cd = c ^ (n & 7);
        breg[q] = *reinterpret_cast<const short8*>(w1t + (size_t)(n0 + n) * VIS + (cd << 3));
    }
    #pragma unroll
    for (int q = 0; q < 4; ++q) {
        const int s = q * 256 + tid, row = s >> 3, c = s & 7;
        *reinterpret_cast<short8*>(&As[0][(row << 6) + (c << 3)]) = pack8(areg[q][0], areg[q][1]);
    }
    #pragma unroll
    for (int q = 0; q < 2; ++q) {
        const int s = q * 256 + tid, n = s >> 3, c = s & 7;
        *reinterpret_cast<short8*>(&Bs[0][(n << 6) + (c << 3)]) = breg[q];
    }
    __syncthreads();

    int cur = 0;
    for (int t = 0; t < VIS / 64; ++t) {
        const int kn = (t + 1) * 64;
        if (t + 1 < VIS / 64) {       // issue next-tile global loads early
            #pragma unroll
            for (int q = 0; q < 4; ++q) {
                const int s = q * 256 + tid, row = s >> 3, c = s & 7, cd = c ^ (row & 7);
                const float* gp = src + (size_t)(m0 + row) * VIS + kn + (cd << 3);
                areg[q][0] = *reinterpret_cast<const float4*>(gp);
                areg[q][1] = *reinterpret_cast<const float4*>(gp + 4);
            }
            #pragma unroll
            for (int q = 0; q < 2; ++q) {
                const int s = q * 256 + tid, n = s >> 3, c = s & 7, cd = c ^ (n & 7);
                breg[q] = *reinterpret_cast<const short8*>(w1t + (size_t)(n0 + n) * VIS + kn + (cd << 3));
            }
        }
        // compute current tile
        #pragma unroll
        for (int k2 = 0; k2 < 2; ++k2) {
            short8 af[4], bfr[2];
            #pragma unroll
            for (int fr = 0; fr < 4; ++fr) {
                const int row = wr * 64 + fr * 16 + (lane & 15);
                const int cw  = ((k2 << 2) + (lane >> 4)) ^ (row & 7);
                af[fr] = *reinterpret_cast<const short8*>(&As[cur][(row << 6) + (cw << 3)]);
            }
            #pragma unroll
            for (int fc = 0; fc < 2; ++fc) {
                const int n  = wc * 32 + fc * 16 + (lane & 15);
                const int cw = ((k2 << 2) + (lane >> 4)) ^ (n & 7);
                bfr[fc] = *reinterpret_cast<const short8*>(&Bs[cur][(n << 6) + (cw << 3)]);
            }
            #pragma unroll
            for (int fr = 0; fr < 4; ++fr)
                #pragma unroll
                for (int fc = 0; fc < 2; ++fc)
                    acc[fr][fc] = __builtin_amdgcn_mfma_f32_16x16x32_bf16(
                        af[fr], bfr[fc], acc[fr][fc], 0, 0, 0);
        }
        if (t + 1 < VIS / 64) {       // write next tile into other buffer
            const int nxt = cur ^ 1;
            #pragma unroll
            for (int q = 0; q < 4; ++q) {
                const int s = q * 256 + tid, row = s >> 3, c = s & 7;
                *reinterpret_cast<short8*>(&As[nxt][(row << 6) + (c << 3)]) =
                    pack8(areg[q][0], areg[q][1]);
            }
            #pragma unroll
            for (int q = 0; q < 2; ++q) {
                const int s = q * 256 + tid, n = s >> 3, c = s & 7;
                *reinterpret_cast<short8*>(&Bs[nxt][(n << 6) + (c << 3)]) = breg[q];
            }
        }
        __syncthreads();
        cur ^= 1;
    }

    // epilogue: bias + relu + bf16 store
    #pragma unroll
    for (int fc = 0; fc < 2; ++fc) {
        const int n = n0 + wc * 32 + fc * 16 + (lane & 15);
        const float bias = b1[n];
        #pragma unroll
        for (int fr = 0; fr < 4; ++fr) {
            const int mb = m0 + wr * 64 + fr * 16 + ((lane >> 4) << 2);
            #pragma unroll
            for (int r = 0; r < 4; ++r) {
                const float v = fmaxf(acc[fr][fc][r] + bias, 0.f);
                h[(size_t)(mb + r) * FEAT + n] = f2bf(v);
            }
        }
    }
}

// ---------------------------------------------------------------------------
// proj: for 8 rows g of h (bf16), out[g][c] = h[g]·wAB[half] + bias row.
// Scatter into Ap (subject rows, i<16) / Bp (object rows).
__global__ __launch_bounds__(192)
void proj(const unsigned short* __restrict__ h, const float* __restrict__ wAB,
          float* __restrict__ Ap, float* __restrict__ Bp) {
    __shared__ float rows[8][FEAT];
    const int g0 = blockIdx.x * 8;
    const int hh = (g0 >> 4) & 1;           // uniform per block (8-aligned)
    const int tid = threadIdx.x;
    for (int s = tid; s < 512; s += 192) {
        const int row = s >> 6, c8 = (s & 63) << 3;
        short8 v = *reinterpret_cast<const short8*>(h + (size_t)(g0 + row) * FEAT + c8);
        #pragma unroll
        for (int e = 0; e < 8; ++e)
            rows[row][c8 + e] = bf2f((unsigned short)v[e]);
    }
    __syncthreads();
    const int c = tid % NTGT, rr = tid / NTGT;   // 8x24 = 192, all active
    const float* wp = wAB + (size_t)hh * 513 * 32 + c;
    float s = 0.f;
    #pragma unroll 8
    for (int k = 0; k < FEAT; ++k)
        s = fmaf(rows[rr][k], wp[(size_t)k * 32], s);
    s += wp[(size_t)512 * 32];                   // cA/cB bias row
    const int g = g0 + rr, bt = g >> 5, i = g & 15;
    float* dst = (g & 16) ? Bp : Ap;
    dst[((size_t)bt * NOBJ + i) * NTGT + c] = s;
}

// ---------------------------------------------------------------------------
__global__ __launch_bounds__(256)
void out_loss_kernel(const float* __restrict__ Ap, const float* __restrict__ Bp,
                     const float* __restrict__ br, const int* __restrict__ tgt,
                     float* __restrict__ out, float* __restrict__ out_tgt,
                     float* __restrict__ acc) {
    const int r   = blockIdx.x * 256 + threadIdx.x;
    const int bt  = r >> 8;
    const int rem = r & 255;
    const int i   = rem >> 4;
    const int j   = rem & 15;
    const float4* ap4 = reinterpret_cast<const float4*>(Ap + ((size_t)bt * NOBJ + i) * NTGT);
    const float4* bp4 = reinterpret_cast<const float4*>(Bp + ((size_t)bt * NOBJ + j) * NTGT);
    const int tg = tgt[r];

    float vals[NTGT];
    float mx = -1e30f, vtg = 0.f;
    #pragma unroll
    for (int q = 0; q < 6; ++q) {
        const float4 a = ap4[q], b = bp4[q];
        vals[q * 4 + 0] = a.x + b.x + br[q * 4 + 0];
        vals[q * 4 + 1] = a.y + b.y + br[q * 4 + 1];
        vals[q * 4 + 2] = a.z + b.z + br[q * 4 + 2];
        vals[q * 4 + 3] = a.w + b.w + br[q * 4 + 3];
    }
    #pragma unroll
    for (int t = 0; t < NTGT; ++t) {
        mx = fmaxf(mx, vals[t]);
        if (t == tg) vtg = vals[t];
    }
    float se = 0.f;
    #pragma unroll
    for (int t = 0; t < NTGT; ++t) se += expf(vals[t] - mx);
    const float lse = mx + logf(se);

    float4* o4 = reinterpret_cast<float4*>(out + (size_t)r * NTGT);
    #pragma unroll
    for (int q = 0; q < 6; ++q)
        o4[q] = make_float4(vals[q * 4], vals[q * 4 + 1], vals[q * 4 + 2], vals[q * 4 + 3]);
    out_tgt[r] = (float)tg;

    const float wcl = (tg == 0) ? 1.f : 100.f;
    float p1 = wcl * (lse - vtg);
    float p2 = wcl;
    #pragma unroll
    for (int off = 32; off > 0; off >>= 1) {
        p1 += __shfl_down(p1, off);
        p2 += __shfl_down(p2, off);
    }
    __shared__ float s1[4], s2[4];
    const int lane = threadIdx.x & 63;
    const int wid  = threadIdx.x >> 6;
    if (lane == 0) { s1[wid] = p1; s2[wid] = p2; }
    __syncthreads();
    if (threadIdx.x == 0) {
        atomicAdd(&acc[0], s1[0] + s1[1] + s1[2] + s1[3]);
        atomicAdd(&acc[1], s2[0] + s2[1] + s2[2] + s2[3]);
    }
}

__global__ void final_loss(const float* __restrict__ acc, float* __restrict__ loss) {
    loss[0] = acc[0] / acc[1];
}

// ---------------------------------------------------------------------------
extern "C" void kernel_launch(void* const* d_in, const int* in_sizes, int n_in,
                              void* d_out, int out_size, void* d_ws, size_t ws_size,
                              hipStream_t stream) {
    const float* src = (const float*)d_in[0];
    const int*   tgt = (const int*)d_in[1];
    const float* w1  = (const float*)d_in[2];
    const float* b1  = (const float*)d_in[3];
    const float* w2  = (const float*)d_in[4];
    const float* b2  = (const float*)d_in[5];
    const float* wf  = (const float*)d_in[6];
    const float* bfv = (const float*)d_in[7];
    const float* wr  = (const float*)d_in[8];
    const float* br  = (const float*)d_in[9];

    float* ws = (float*)d_ws;
    // layout (f32 units)
    unsigned short* w1t = (unsigned short*)(ws);             // 512x2048 bf16
    unsigned short* h   = (unsigned short*)(ws + 524288);    // 4096x512 bf16
    float* t1  = ws + 1572864;                               // 2*513*32
    float* wAB = ws + 1605696;                               // 2*513*32
    float* acc = ws + 1638528;                               // 2 (+2 pad)
    float* Ap  = ws + 1638532;                               // 2048*24
    float* Bp  = ws + 1687684;                               // 2048*24

    float* out_logits = (float*)d_out;
    float* out_tgt    = out_logits + (size_t)EROWS * NTGT;
    float* out_lossp  = out_tgt + EROWS;

    zero_kernel<<<257, 256, 0, stream>>>(t1, 65666);   // t1 + wAB + acc
    wtrans<<<dim3(64, 16), 256, 0, stream>>>(w1, w1t);
    wchain1<<<dim3(65, 4, 2), dim3(32, 8), 0, stream>>>(wf, bfv, wr, t1);
    wchain2<<<dim3(65, 4, 2), dim3(32, 8), 0, stream>>>(w2, b2, t1, wAB);
    gemm1<<<256, 256, 0, stream>>>(src, w1t, b1, h);
    proj<<<512, 192, 0, stream>>>(h, wAB, Ap, Bp);
    out_loss_kernel<<<EROWS / 256, 256, 0, stream>>>(Ap, Bp, br, tgt,
                                                     out_logits, out_tgt, acc);
    final_loss<<<1, 1, 0, stream>>>(acc, out_lossp);
}

// Round 3
// 163.656 us; speedup vs baseline: 1.9325x; 1.0526x over previous
//
#include <hip/hip_runtime.h>
#include <cstddef>
#include <cstdint>

#define NOBJ   16
#define FEAT   512
#define VIS    2048
#define NTGT   24
#define MROWS  4096
#define EROWS  32768

typedef __attribute__((ext_vector_type(8))) short short8;
typedef __attribute__((ext_vector_type(4))) float f32x4;

__device__ __forceinline__ unsigned short f2bf(float f) {
    union { float f; unsigned int i; } v; v.f = f;
    const unsigned int x = v.i;
    return (unsigned short)((x + 0x7fffu + ((x >> 16) & 1u)) >> 16);  // RTNE
}
__device__ __forceinline__ short8 pack8(const float4 a, const float4 b) {
    short8 r;
    r[0] = (short)f2bf(a.x); r[1] = (short)f2bf(a.y);
    r[2] = (short)f2bf(a.z); r[3] = (short)f2bf(a.w);
    r[4] = (short)f2bf(b.x); r[5] = (short)f2bf(b.y);
    r[6] = (short)f2bf(b.z); r[7] = (short)f2bf(b.w);
    return r;
}

// ---------------------------------------------------------------------------
// w1 (2048x512 f32) -> w1t (512x2048 bf16), transposed
__global__ __launch_bounds__(256)
void wtrans(const float* __restrict__ w1, unsigned short* __restrict__ w1t) {
    __shared__ float tile[32][33];
    const int k0 = blockIdx.x * 32;
    const int n0 = blockIdx.y * 32;
    const int tx = threadIdx.x & 31, ty = threadIdx.x >> 5;
    #pragma unroll
    for (int r = 0; r < 32; r += 8)
        tile[ty + r][tx] = w1[(size_t)(k0 + ty + r) * FEAT + n0 + tx];
    __syncthreads();
    #pragma unroll
    for (int r = 0; r < 32; r += 8)
        w1t[(size_t)(n0 + ty + r) * VIS + k0 + tx] = f2bf(tile[tx][ty + r]);
}

// ---------------------------------------------------------------------------
// wchain1: t1[h][krow][c] = sum_j rowk[j] * wr[h][j][c];  rowk = wf row (or bf).
// wr half staged in LDS (48 KB). No atomics: each output written once.
__global__ __launch_bounds__(256)
void wchain1(const float* __restrict__ wf, const float* __restrict__ bfv,
             const float* __restrict__ wr, float* __restrict__ t1) {
    __shared__ float wrs[FEAT * NTGT];     // [j][c], 48 KB
    const int h = blockIdx.y;
    const float* wrh = wr + (size_t)h * FEAT * NTGT;
    for (int idx = threadIdx.y * 32 + threadIdx.x; idx < FEAT * NTGT; idx += 256)
        wrs[idx] = wrh[idx];
    __syncthreads();
    const int c    = threadIdx.x;                    // 0..31
    const int krow = blockIdx.x * 8 + threadIdx.y;   // 0..519
    if (krow > 512) return;
    const float* rowp = (krow < 512) ? (wf + (size_t)krow * FEAT) : bfv;
    const int ce = (c < NTGT) ? c : NTGT - 1;
    float s = 0.f;
    #pragma unroll 8
    for (int j = 0; j < FEAT; ++j)
        s = fmaf(rowp[j], wrs[j * NTGT + ce], s);
    if (c < NTGT) t1[((size_t)h * 513 + krow) * 32 + c] = s;
}

// wchain2: wABt[q=h*24+c][r] = bf16( sum_k w2[r][k] * t1[h][k][c] );
// bias row (r==512, rowp=b2): biasAB[q] = s + t1[h][512][c].
__global__ __launch_bounds__(256)
void wchain2(const float* __restrict__ w2, const float* __restrict__ b2,
             const float* __restrict__ t1, unsigned short* __restrict__ wABt,
             float* __restrict__ biasAB) {
    __shared__ float t1s[FEAT * NTGT];     // [k][c], 48 KB
    const int h = blockIdx.y;
    for (int idx = threadIdx.y * 32 + threadIdx.x; idx < FEAT * NTGT; idx += 256) {
        const int row = idx / NTGT, col = idx - row * NTGT;
        t1s[idx] = t1[((size_t)h * 513 + row) * 32 + col];
    }
    __syncthreads();
    const int c = threadIdx.x;
    const int r = blockIdx.x * 8 + threadIdx.y;
    if (r > 512) return;
    const float* rowp = (r < 512) ? (w2 + (size_t)r * FEAT) : b2;
    const int ce = (c < NTGT) ? c : NTGT - 1;
    float s = 0.f;
    #pragma unroll 8
    for (int k = 0; k < FEAT; ++k)
        s = fmaf(rowp[k], t1s[k * NTGT + ce], s);
    if (c < NTGT) {
        const int q = h * NTGT + c;
        if (r < 512) wABt[(size_t)q * FEAT + r] = f2bf(s);
        else         biasAB[q] = s + t1[((size_t)h * 513 + 512) * 32 + c];
    }
}

// ---------------------------------------------------------------------------
// GEMM1: h = relu(src(4096x2048 f32->bf16) @ w1 + b1).  BM=128 BN=32 BK=64,
// grid 512 (2 blocks/CU), 4 waves each 32x32 (2x2 frags), dbuf LDS, XOR swizzle.
__global__ __launch_bounds__(256)
void gemm1(const float* __restrict__ src, const unsigned short* __restrict__ w1t,
           const float* __restrict__ b1, unsigned short* __restrict__ h) {
    __shared__ __align__(16) unsigned short As[2][128 * 64];  // 32 KB
    __shared__ __align__(16) unsigned short Bs[2][32 * 64];   //  8 KB

    // XCD-aware: 16 col-blocks x 4 row-panels per XCD.
    const int bid = blockIdx.x;
    const int xcd = bid & 7;
    const int k8  = bid >> 3;               // 0..63
    const int xb  = k8 & 15;                // col block 0..15
    const int yb  = (xcd << 2) | (k8 >> 4); // row block 0..31
    const int m0 = yb * 128;
    const int n0 = xb * 32;

    const int tid  = threadIdx.x;
    const int lane = tid & 63;
    const int wid  = tid >> 6;              // wave owns rows [wid*32, +32)

    f32x4  acc[2][2] = {};
    float4 areg[4][2];
    short8 breg;

    // prologue: tile 0 -> regs -> LDS buf 0
    #pragma unroll
    for (int q = 0; q < 4; ++q) {
        const int s = q * 256 + tid, row = s >> 3, c = s & 7, cd = c ^ (row & 7);
        const float* gp = src + (size_t)(m0 + row) * VIS + (cd << 3);
        areg[q][0] = *reinterpret_cast<const float4*>(gp);
        areg[q][1] = *reinterpret_cast<const float4*>(gp + 4);
    }
    {
        const int n = tid >> 3, c = tid & 7, cd = c ^ (n & 7);
        breg = *reinterpret_cast<const short8*>(w1t + (size_t)(n0 + n) * VIS + (cd << 3));
    }
    #pragma unroll
    for (int q = 0; q < 4; ++q) {
        const int s = q * 256 + tid, row = s >> 3, c = s & 7;
        *reinterpret_cast<short8*>(&As[0][(row << 6) + (c << 3)]) = pack8(areg[q][0], areg[q][1]);
    }
    {
        const int n = tid >> 3, c = tid & 7;
        *reinterpret_cast<short8*>(&Bs[0][(n << 6) + (c << 3)]) = breg;
    }
    __syncthreads();

    int cur = 0;
    for (int t = 0; t < VIS / 64; ++t) {
        const int kn = (t + 1) * 64;
        if (t + 1 < VIS / 64) {
            #pragma unroll
            for (int q = 0; q < 4; ++q) {
                const int s = q * 256 + tid, row = s >> 3, c = s & 7, cd = c ^ (row & 7);
                const float* gp = src + (size_t)(m0 + row) * VIS + kn + (cd << 3);
                areg[q][0] = *reinterpret_cast<const float4*>(gp);
                areg[q][1] = *reinterpret_cast<const float4*>(gp + 4);
            }
            const int n = tid >> 3, c = tid & 7, cd = c ^ (n & 7);
            breg = *reinterpret_cast<const short8*>(w1t + (size_t)(n0 + n) * VIS + kn + (cd << 3));
        }
        #pragma unroll
        for (int k2 = 0; k2 < 2; ++k2) {
            short8 af[2], bfr[2];
            #pragma unroll
            for (int fr = 0; fr < 2; ++fr) {
                const int row = wid * 32 + fr * 16 + (lane & 15);
                const int cw  = ((k2 << 2) + (lane >> 4)) ^ (row & 7);
                af[fr] = *reinterpret_cast<const short8*>(&As[cur][(row << 6) + (cw << 3)]);
            }
            #pragma unroll
            for (int fc = 0; fc < 2; ++fc) {
                const int n  = fc * 16 + (lane & 15);
                const int cw = ((k2 << 2) + (lane >> 4)) ^ (n & 7);
                bfr[fc] = *reinterpret_cast<const short8*>(&Bs[cur][(n << 6) + (cw << 3)]);
            }
            #pragma unroll
            for (int fr = 0; fr < 2; ++fr)
                #pragma unroll
                for (int fc = 0; fc < 2; ++fc)
                    acc[fr][fc] = __builtin_amdgcn_mfma_f32_16x16x32_bf16(
                        af[fr], bfr[fc], acc[fr][fc], 0, 0, 0);
        }
        if (t + 1 < VIS / 64) {
            const int nxt = cur ^ 1;
            #pragma unroll
            for (int q = 0; q < 4; ++q) {
                const int s = q * 256 + tid, row = s >> 3, c = s & 7;
                *reinterpret_cast<short8*>(&As[nxt][(row << 6) + (c << 3)]) =
                    pack8(areg[q][0], areg[q][1]);
            }
            const int n = tid >> 3, c = tid & 7;
            *reinterpret_cast<short8*>(&Bs[nxt][(n << 6) + (c << 3)]) = breg;
        }
        __syncthreads();
        cur ^= 1;
    }

    #pragma unroll
    for (int fc = 0; fc < 2; ++fc) {
        const int n = n0 + fc * 16 + (lane & 15);
        const float bias = b1[n];
        #pragma unroll
        for (int fr = 0; fr < 2; ++fr) {
            const int mb = m0 + wid * 32 + fr * 16 + ((lane >> 4) << 2);
            #pragma unroll
            for (int r = 0; r < 4; ++r) {
                const float v = fmaxf(acc[fr][fc][r] + bias, 0.f);
                h[(size_t)(mb + r) * FEAT + n] = f2bf(v);
            }
        }
    }
}

// ---------------------------------------------------------------------------
// projG: P(4096x64 f32) = h(4096x512 bf16) @ wABt^T + biasAB.
// BM=32, BN=64(48 valid), BK=64; B (64x512) persistent in LDS; grid 128.
__global__ __launch_bounds__(256)
void projG(const unsigned short* __restrict__ h, const unsigned short* __restrict__ wABt,
           const float* __restrict__ biasAB, float* __restrict__ P) {
    __shared__ __align__(16) unsigned short Bs[64 * 512];  // 64 KB
    __shared__ __align__(16) unsigned short As[32 * 64];   //  4 KB
    const int tid  = threadIdx.x;
    const int lane = tid & 63;
    const int wid  = tid >> 6;            // n-quarter
    const int m0   = blockIdx.x * 32;

    // stage whole B once (swizzled source -> linear LDS; read re-applies XOR)
    #pragma unroll
    for (int q = 0; q < 16; ++q) {
        const int e = q * 256 + tid;
        const int n = e >> 6, cc = e & 63, cd = cc ^ (n & 7);
        *reinterpret_cast<short8*>(&Bs[(n << 9) + (cc << 3)]) =
            *reinterpret_cast<const short8*>(wABt + ((size_t)n << 9) + (cd << 3));
    }
    __syncthreads();

    f32x4 acc[2] = {};
    for (int t = 0; t < FEAT / 64; ++t) {
        const int kt = t * 64;
        {
            const int row = tid >> 3, c = tid & 7, cd = c ^ (row & 7);
            *reinterpret_cast<short8*>(&As[(row << 6) + (c << 3)]) =
                *reinterpret_cast<const short8*>(h + (size_t)(m0 + row) * FEAT + kt + (cd << 3));
        }
        __syncthreads();
        #pragma unroll
        for (int k2 = 0; k2 < 2; ++k2) {
            short8 af[2], bfr;
            #pragma unroll
            for (int fr = 0; fr < 2; ++fr) {
                const int row = fr * 16 + (lane & 15);
                const int cw  = ((k2 << 2) + (lane >> 4)) ^ (row & 7);
                af[fr] = *reinterpret_cast<const short8*>(&As[(row << 6) + (cw << 3)]);
            }
            {
                const int n     = wid * 16 + (lane & 15);
                const int chunk = t * 8 + k2 * 4 + (lane >> 4);
                const int cw    = chunk ^ (n & 7);
                bfr = *reinterpret_cast<const short8*>(&Bs[(n << 9) + (cw << 3)]);
            }
            #pragma unroll
            for (int fr = 0; fr < 2; ++fr)
                acc[fr] = __builtin_amdgcn_mfma_f32_16x16x32_bf16(af[fr], bfr, acc[fr], 0, 0, 0);
        }
        __syncthreads();
    }

    const int n = wid * 16 + (lane & 15);
    const float bias = biasAB[n];
    #pragma unroll
    for (int fr = 0; fr < 2; ++fr) {
        const int rb = fr * 16 + ((lane >> 4) << 2);
        #pragma unroll
        for (int r = 0; r < 4; ++r)
            P[(size_t)(m0 + rb + r) * 64 + n] = acc[fr][r] + bias;
    }
}

// ---------------------------------------------------------------------------
// out_loss: one block per bt (128 blocks). Stage P rows, assemble logits,
// weighted-CE partials per block (no atomics).
__global__ __launch_bounds__(256)
void out_loss_kernel(const float* __restrict__ P, const float* __restrict__ br,
                     const int* __restrict__ tgt, float* __restrict__ out,
                     float* __restrict__ out_tgt, float* __restrict__ partials) {
    __shared__ float sm[32][49];
    const int bt  = blockIdx.x;
    const int tid = threadIdx.x;
    for (int idx = tid; idx < 32 * 48; idx += 256) {
        const int row = idx / 48, col = idx - row * 48;
        sm[row][col] = P[(size_t)(bt * 32 + row) * 64 + col];
    }
    __syncthreads();

    const int r  = bt * 256 + tid;
    const int i  = tid >> 4, j = tid & 15;
    const int tg = tgt[r];

    float vals[NTGT];
    float mx = -1e30f, vtg = 0.f;
    #pragma unroll
    for (int t = 0; t < NTGT; ++t) {
        const float v = sm[i][t] + sm[16 + j][24 + t] + br[t];
        vals[t] = v;
        mx = fmaxf(mx, v);
        if (t == tg) vtg = v;
    }
    float se = 0.f;
    #pragma unroll
    for (int t = 0; t < NTGT; ++t) se += expf(vals[t] - mx);
    const float lse = mx + logf(se);

    float4* o4 = reinterpret_cast<float4*>(out + (size_t)r * NTGT);
    #pragma unroll
    for (int q = 0; q < 6; ++q)
        o4[q] = make_float4(vals[q * 4], vals[q * 4 + 1], vals[q * 4 + 2], vals[q * 4 + 3]);
    out_tgt[r] = (float)tg;

    const float wcl = (tg == 0) ? 1.f : 100.f;
    float p1 = wcl * (lse - vtg);
    float p2 = wcl;
    #pragma unroll
    for (int off = 32; off > 0; off >>= 1) {
        p1 += __shfl_down(p1, off);
        p2 += __shfl_down(p2, off);
    }
    __shared__ float s1[4], s2[4];
    const int lane = tid & 63, wv = tid >> 6;
    if (lane == 0) { s1[wv] = p1; s2[wv] = p2; }
    __syncthreads();
    if (tid == 0) {
        partials[bt]       = s1[0] + s1[1] + s1[2] + s1[3];
        partials[128 + bt] = s2[0] + s2[1] + s2[2] + s2[3];
    }
}

__global__ void final_loss(const float* __restrict__ partials, float* __restrict__ loss) {
    const int t = threadIdx.x;                       // 64 threads
    float a = partials[t] + partials[t + 64];
    float b = partials[128 + t] + partials[192 + t];
    #pragma unroll
    for (int off = 32; off > 0; off >>= 1) {
        a += __shfl_down(a, off);
        b += __shfl_down(b, off);
    }
    if (t == 0) loss[0] = a / b;
}

// ---------------------------------------------------------------------------
extern "C" void kernel_launch(void* const* d_in, const int* in_sizes, int n_in,
                              void* d_out, int out_size, void* d_ws, size_t ws_size,
                              hipStream_t stream) {
    const float* src = (const float*)d_in[0];
    const int*   tgt = (const int*)d_in[1];
    const float* w1  = (const float*)d_in[2];
    const float* b1  = (const float*)d_in[3];
    const float* w2  = (const float*)d_in[4];
    const float* b2  = (const float*)d_in[5];
    const float* wf  = (const float*)d_in[6];
    const float* bfv = (const float*)d_in[7];
    const float* wr  = (const float*)d_in[8];
    const float* br  = (const float*)d_in[9];

    float* ws = (float*)d_ws;
    unsigned short* w1t  = (unsigned short*)(ws);              // 512x2048 bf16
    unsigned short* h    = (unsigned short*)(ws + 524288);     // 4096x512 bf16
    float*          t1   = ws + 1572864;                       // 2*513*32 f32
    unsigned short* wABt = (unsigned short*)(ws + 1605696);    // 64x512 bf16
    float*          biasAB = ws + 1622080;                     // 64 f32
    float*          P    = ws + 1622144;                       // 4096x64 f32
    float*          parts = ws + 1884288;                      // 256 f32

    float* out_logits = (float*)d_out;
    float* out_tgt    = out_logits + (size_t)EROWS * NTGT;
    float* out_lossp  = out_tgt + EROWS;

    wtrans<<<dim3(64, 16), 256, 0, stream>>>(w1, w1t);
    wchain1<<<dim3(65, 2), dim3(32, 8), 0, stream>>>(wf, bfv, wr, t1);
    wchain2<<<dim3(65, 2), dim3(32, 8), 0, stream>>>(w2, b2, t1, wABt, biasAB);
    gemm1<<<512, 256, 0, stream>>>(src, w1t, b1, h);
    projG<<<128, 256, 0, stream>>>(h, wABt, biasAB, P);
    out_loss_kernel<<<128, 256, 0, stream>>>(P, br, tgt, out_logits, out_tgt, parts);
    final_loss<<<1, 64, 0, stream>>>(parts, out_lossp);
}

// Round 4
// 156.474 us; speedup vs baseline: 2.0212x; 1.0459x over previous
//
#include <hip/hip_runtime.h>
#include <cstddef>
#include <cstdint>

#define NOBJ   16
#define FEAT   512
#define VIS    2048
#define NTGT   24
#define MROWS  4096
#define EROWS  32768

typedef __attribute__((ext_vector_type(8))) short short8;
typedef __attribute__((ext_vector_type(4))) float f32x4;

__device__ __forceinline__ float bf2f(unsigned short u) {
    union { unsigned int i; float f; } v; v.i = ((unsigned int)u) << 16; return v.f;
}
__device__ __forceinline__ unsigned short f2bf(float f) {
    union { float f; unsigned int i; } v; v.f = f;
    const unsigned int x = v.i;
    return (unsigned short)((x + 0x7fffu + ((x >> 16) & 1u)) >> 16);  // RTNE
}
__device__ __forceinline__ short8 pack8(const float4 a, const float4 b) {
    short8 r;
    r[0] = (short)f2bf(a.x); r[1] = (short)f2bf(a.y);
    r[2] = (short)f2bf(a.z); r[3] = (short)f2bf(a.w);
    r[4] = (short)f2bf(b.x); r[5] = (short)f2bf(b.y);
    r[6] = (short)f2bf(b.z); r[7] = (short)f2bf(b.w);
    return r;
}

// ---------------------------------------------------------------------------
// prep1: [0,1024) wtrans  |  [1024,1154) wchain1
// wtrans: w1 (2048x512 f32) -> w1t (512x2048 bf16)
// wchain1: t1[h][krow][c] = sum_j rowk[j]*wr[h][j][c]; rowk = wf row (or bf)
__global__ __launch_bounds__(256)
void prep1(const float* __restrict__ w1, unsigned short* __restrict__ w1t,
           const float* __restrict__ wf, const float* __restrict__ bfv,
           const float* __restrict__ wr, float* __restrict__ t1) {
    __shared__ float shbuf[FEAT * NTGT];   // 48 KB, reused by both branches
    const int b   = blockIdx.x;
    const int tid = threadIdx.x;
    if (b < 1024) {
        float (*tile)[33] = (float(*)[33])shbuf;
        const int k0 = (b & 63) * 32;
        const int n0 = (b >> 6) * 32;
        const int tx = tid & 31, ty = tid >> 5;
        #pragma unroll
        for (int r = 0; r < 32; r += 8)
            tile[ty + r][tx] = w1[(size_t)(k0 + ty + r) * FEAT + n0 + tx];
        __syncthreads();
        #pragma unroll
        for (int r = 0; r < 32; r += 8)
            w1t[(size_t)(n0 + ty + r) * VIS + k0 + tx] = f2bf(tile[tx][ty + r]);
    } else {
        const int bb = b - 1024;           // 0..129
        const int h  = bb & 1;
        const float* wrh = wr + (size_t)h * FEAT * NTGT;
        for (int idx = tid; idx < FEAT * NTGT; idx += 256)
            shbuf[idx] = wrh[idx];
        __syncthreads();
        const int c    = tid & 31;
        const int krow = (bb >> 1) * 8 + (tid >> 5);   // 0..519
        if (krow > 512) return;
        const float* rowp = (krow < 512) ? (wf + (size_t)krow * FEAT) : bfv;
        const int ce = (c < NTGT) ? c : NTGT - 1;
        float s = 0.f;
        #pragma unroll 8
        for (int j = 0; j < FEAT; ++j)
            s = fmaf(rowp[j], shbuf[j * NTGT + ce], s);
        if (c < NTGT) t1[((size_t)h * 513 + krow) * 32 + c] = s;
    }
}

// ---------------------------------------------------------------------------
// prep2: [0,1024) zero P  |  [1024,1154) wchain2
// wchain2: wABt[q=h*24+c][r] = bf16(sum_k w2[r][k]*t1[h][k][c]); r==512 -> biasAB
__global__ __launch_bounds__(256)
void prep2(const float* __restrict__ w2, const float* __restrict__ b2,
           const float* __restrict__ t1, unsigned short* __restrict__ wABt,
           float* __restrict__ biasAB, float* __restrict__ P) {
    __shared__ float shbuf[FEAT * NTGT];   // 48 KB
    const int b   = blockIdx.x;
    const int tid = threadIdx.x;
    if (b < 1024) {
        P[(size_t)b * 256 + tid] = 0.f;    // 4096*64 f32
        return;
    }
    const int bb = b - 1024;
    const int h  = bb & 1;
    for (int idx = tid; idx < FEAT * NTGT; idx += 256) {
        const int row = idx / NTGT, col = idx - row * NTGT;
        shbuf[idx] = t1[((size_t)h * 513 + row) * 32 + col];
    }
    __syncthreads();
    const int c = tid & 31;
    const int r = (bb >> 1) * 8 + (tid >> 5);
    if (r > 512) return;
    const float* rowp = (r < 512) ? (w2 + (size_t)r * FEAT) : b2;
    const int ce = (c < NTGT) ? c : NTGT - 1;
    float s = 0.f;
    #pragma unroll 8
    for (int k = 0; k < FEAT; ++k)
        s = fmaf(rowp[k], shbuf[k * NTGT + ce], s);
    if (c < NTGT) {
        const int q = h * NTGT + c;
        if (r < 512) wABt[(size_t)q * FEAT + r] = f2bf(s);
        else         biasAB[q] = s + t1[((size_t)h * 513 + 512) * 32 + c];
    }
}

// ---------------------------------------------------------------------------
// gemm1f: h = relu(src @ w1 + b1) computed per 64x32 tile, then FUSED
// projection: atomicAdd P[64x48] += h_tile(64x32) @ wABt[:, n0:n0+32]^T.
// BM=64 BN=32 BK=64, grid 1024 (4 blocks/CU), 4 waves of 32x16, dbuf LDS,
// XOR swizzle; epilogue reuses As[0] as Ht[64][40] bf16.
__global__ __launch_bounds__(256)
void gemm1f(const float* __restrict__ src, const unsigned short* __restrict__ w1t,
            const float* __restrict__ b1, const unsigned short* __restrict__ wABt,
            float* __restrict__ P) {
    __shared__ __align__(16) unsigned short As[2][64 * 64];  // 16 KB
    __shared__ __align__(16) unsigned short Bs[2][32 * 64];  //  8 KB

    // XCD-aware: each XCD gets 8 m-panels x 16 n-panels (A panel set = 4 MB).
    const int bid = blockIdx.x;
    const int xcd = bid & 7;
    const int k8  = bid >> 3;               // 0..127
    const int xb  = k8 & 15;                // n-panel 0..15
    const int yb  = (xcd << 3) | (k8 >> 4); // m-panel 0..63
    const int m0 = yb * 64;
    const int n0 = xb * 32;

    const int tid  = threadIdx.x;
    const int lane = tid & 63;
    const int wid  = tid >> 6;
    const int wr = wid >> 1, wc = wid & 1;  // wave tile: rows wr*32.., cols wc*16..

    f32x4  acc[2] = {};
    float4 areg[2][2];
    short8 breg;

    // prologue: stage tile 0
    #pragma unroll
    for (int q = 0; q < 2; ++q) {
        const int s = q * 256 + tid, row = s >> 3, c = s & 7, cd = c ^ (row & 7);
        const float* gp = src + (size_t)(m0 + row) * VIS + (cd << 3);
        areg[q][0] = *reinterpret_cast<const float4*>(gp);
        areg[q][1] = *reinterpret_cast<const float4*>(gp + 4);
    }
    {
        const int n = tid >> 3, c = tid & 7, cd = c ^ (n & 7);
        breg = *reinterpret_cast<const short8*>(w1t + (size_t)(n0 + n) * VIS + (cd << 3));
    }
    #pragma unroll
    for (int q = 0; q < 2; ++q) {
        const int s = q * 256 + tid, row = s >> 3, c = s & 7;
        *reinterpret_cast<short8*>(&As[0][(row << 6) + (c << 3)]) = pack8(areg[q][0], areg[q][1]);
    }
    {
        const int n = tid >> 3, c = tid & 7;
        *reinterpret_cast<short8*>(&Bs[0][(n << 6) + (c << 3)]) = breg;
    }
    __syncthreads();

    int cur = 0;
    for (int t = 0; t < VIS / 64; ++t) {
        const int kn = (t + 1) * 64;
        if (t + 1 < VIS / 64) {
            #pragma unroll
            for (int q = 0; q < 2; ++q) {
                const int s = q * 256 + tid, row = s >> 3, c = s & 7, cd = c ^ (row & 7);
                const float* gp = src + (size_t)(m0 + row) * VIS + kn + (cd << 3);
                areg[q][0] = *reinterpret_cast<const float4*>(gp);
                areg[q][1] = *reinterpret_cast<const float4*>(gp + 4);
            }
            const int n = tid >> 3, c = tid & 7, cd = c ^ (n & 7);
            breg = *reinterpret_cast<const short8*>(w1t + (size_t)(n0 + n) * VIS + kn + (cd << 3));
        }
        #pragma unroll
        for (int k2 = 0; k2 < 2; ++k2) {
            short8 af[2], bfr;
            #pragma unroll
            for (int fr = 0; fr < 2; ++fr) {
                const int row = wr * 32 + fr * 16 + (lane & 15);
                const int cw  = ((k2 << 2) + (lane >> 4)) ^ (row & 7);
                af[fr] = *reinterpret_cast<const short8*>(&As[cur][(row << 6) + (cw << 3)]);
            }
            {
                const int n  = wc * 16 + (lane & 15);
                const int cw = ((k2 << 2) + (lane >> 4)) ^ (n & 7);
                bfr = *reinterpret_cast<const short8*>(&Bs[cur][(n << 6) + (cw << 3)]);
            }
            #pragma unroll
            for (int fr = 0; fr < 2; ++fr)
                acc[fr] = __builtin_amdgcn_mfma_f32_16x16x32_bf16(af[fr], bfr, acc[fr], 0, 0, 0);
        }
        if (t + 1 < VIS / 64) {
            const int nxt = cur ^ 1;
            #pragma unroll
            for (int q = 0; q < 2; ++q) {
                const int s = q * 256 + tid, row = s >> 3, c = s & 7;
                *reinterpret_cast<short8*>(&As[nxt][(row << 6) + (c << 3)]) =
                    pack8(areg[q][0], areg[q][1]);
            }
            const int n = tid >> 3, c = tid & 7;
            *reinterpret_cast<short8*>(&Bs[nxt][(n << 6) + (c << 3)]) = breg;
        }
        __syncthreads();
        cur ^= 1;
    }

    // ---------------- fused projection epilogue ----------------
    // B-frags direct from global wABt ([q][n] layout == B-fragment layout).
    short8 bq[3];
    #pragma unroll
    for (int t3 = 0; t3 < 3; ++t3)
        bq[t3] = *reinterpret_cast<const short8*>(
            wABt + (size_t)(t3 * 16 + (lane & 15)) * FEAT + n0 + ((lane >> 4) << 3));

    // bias + relu + pack -> Ht[64][40] bf16 (reuse As[0])
    unsigned short* Ht = &As[0][0];
    {
        const int nl   = wc * 16 + (lane & 15);
        const float bias = b1[n0 + nl];
        #pragma unroll
        for (int fr = 0; fr < 2; ++fr) {
            const int ml = wr * 32 + fr * 16 + ((lane >> 4) << 2);
            #pragma unroll
            for (int r = 0; r < 4; ++r) {
                const float v = fmaxf(acc[fr][r] + bias, 0.f);
                Ht[(ml + r) * 40 + nl] = f2bf(v);
            }
        }
    }
    __syncthreads();

    // Each wave: m-tile wid (16 rows) x 48 cols, K=32 (the block's n-slice).
    short8 aep;
    {
        const int m = wid * 16 + (lane & 15);
        aep = *reinterpret_cast<const short8*>(&Ht[m * 40 + ((lane >> 4) << 3)]);
    }
    const f32x4 pz = {0.f, 0.f, 0.f, 0.f};
    #pragma unroll
    for (int t3 = 0; t3 < 3; ++t3) {
        f32x4 pp = __builtin_amdgcn_mfma_f32_16x16x32_bf16(aep, bq[t3], pz, 0, 0, 0);
        const int q  = t3 * 16 + (lane & 15);
        const int mb = m0 + wid * 16 + ((lane >> 4) << 2);
        #pragma unroll
        for (int r = 0; r < 4; ++r)
            atomicAdd(&P[(size_t)(mb + r) * 64 + q], pp[r]);
    }
}

// ---------------------------------------------------------------------------
// out_loss: one block per bt. vals = P[subj][t] + P[obj][24+t] + cvec[t].
__global__ __launch_bounds__(256)
void out_loss_kernel(const float* __restrict__ P, const float* __restrict__ br,
                     const float* __restrict__ biasAB, const int* __restrict__ tgt,
                     float* __restrict__ out, float* __restrict__ out_tgt,
                     float* __restrict__ partials) {
    __shared__ float sm[32][49];
    const int bt  = blockIdx.x;
    const int tid = threadIdx.x;
    for (int idx = tid; idx < 32 * 48; idx += 256) {
        const int row = idx / 48, col = idx - row * 48;
        sm[row][col] = P[(size_t)(bt * 32 + row) * 64 + col];
    }
    __syncthreads();

    const int r  = bt * 256 + tid;
    const int i  = tid >> 4, j = tid & 15;
    const int tg = tgt[r];

    float vals[NTGT];
    float mx = -1e30f, vtg = 0.f;
    #pragma unroll
    for (int t = 0; t < NTGT; ++t) {
        const float cv = br[t] + biasAB[t] + biasAB[24 + t];
        const float v  = sm[i][t] + sm[16 + j][24 + t] + cv;
        vals[t] = v;
        mx = fmaxf(mx, v);
        if (t == tg) vtg = v;
    }
    float se = 0.f;
    #pragma unroll
    for (int t = 0; t < NTGT; ++t) se += expf(vals[t] - mx);
    const float lse = mx + logf(se);

    float4* o4 = reinterpret_cast<float4*>(out + (size_t)r * NTGT);
    #pragma unroll
    for (int q = 0; q < 6; ++q)
        o4[q] = make_float4(vals[q * 4], vals[q * 4 + 1], vals[q * 4 + 2], vals[q * 4 + 3]);
    out_tgt[r] = (float)tg;

    const float wcl = (tg == 0) ? 1.f : 100.f;
    float p1 = wcl * (lse - vtg);
    float p2 = wcl;
    #pragma unroll
    for (int off = 32; off > 0; off >>= 1) {
        p1 += __shfl_down(p1, off);
        p2 += __shfl_down(p2, off);
    }
    __shared__ float s1[4], s2[4];
    const int lane = tid & 63, wv = tid >> 6;
    if (lane == 0) { s1[wv] = p1; s2[wv] = p2; }
    __syncthreads();
    if (tid == 0) {
        partials[bt]       = s1[0] + s1[1] + s1[2] + s1[3];
        partials[128 + bt] = s2[0] + s2[1] + s2[2] + s2[3];
    }
}

__global__ void final_loss(const float* __restrict__ partials, float* __restrict__ loss) {
    const int t = threadIdx.x;                       // 64 threads
    float a = partials[t] + partials[t + 64];
    float b = partials[128 + t] + partials[192 + t];
    #pragma unroll
    for (int off = 32; off > 0; off >>= 1) {
        a += __shfl_down(a, off);
        b += __shfl_down(b, off);
    }
    if (t == 0) loss[0] = a / b;
}

// ---------------------------------------------------------------------------
extern "C" void kernel_launch(void* const* d_in, const int* in_sizes, int n_in,
                              void* d_out, int out_size, void* d_ws, size_t ws_size,
                              hipStream_t stream) {
    const float* src = (const float*)d_in[0];
    const int*   tgt = (const int*)d_in[1];
    const float* w1  = (const float*)d_in[2];
    const float* b1  = (const float*)d_in[3];
    const float* w2  = (const float*)d_in[4];
    const float* b2  = (const float*)d_in[5];
    const float* wf  = (const float*)d_in[6];
    const float* bfv = (const float*)d_in[7];
    const float* wr  = (const float*)d_in[8];
    const float* br  = (const float*)d_in[9];

    float* ws = (float*)d_ws;
    unsigned short* w1t  = (unsigned short*)(ws);            // 512x2048 bf16
    float*          t1   = ws + 524288;                      // 2*513*32 f32
    unsigned short* wABt = (unsigned short*)(ws + 557056);   // 48x512 bf16
    float*          biasAB = ws + 569344;                    // 48 f32
    float*          P    = ws + 569408;                      // 4096x64 f32
    float*          parts = ws + 831552;                     // 256 f32

    float* out_logits = (float*)d_out;
    float* out_tgt    = out_logits + (size_t)EROWS * NTGT;
    float* out_lossp  = out_tgt + EROWS;

    prep1<<<1154, 256, 0, stream>>>(w1, w1t, wf, bfv, wr, t1);
    prep2<<<1154, 256, 0, stream>>>(w2, b2, t1, wABt, biasAB, P);
    gemm1f<<<1024, 256, 0, stream>>>(src, w1t, b1, wABt, P);
    out_loss_kernel<<<128, 256, 0, stream>>>(P, br, biasAB, tgt,
                                             out_logits, out_tgt, parts);
    final_loss<<<1, 64, 0, stream>>>(parts, out_lossp);
}